// Round 2
// baseline (231.624 us; speedup 1.0000x reference)
//
#include <hip/hip_runtime.h>
#include <stdint.h>

typedef __attribute__((ext_vector_type(8))) short short8;
typedef __attribute__((ext_vector_type(4))) short short4v;
typedef __attribute__((ext_vector_type(4))) float f32x4;
typedef __attribute__((ext_vector_type(16))) float f32x16;
typedef __attribute__((ext_vector_type(2))) unsigned int u32x2;
typedef __attribute__((ext_vector_type(4))) unsigned int u32x4;
typedef unsigned int u32;
typedef const __attribute__((address_space(1))) u32* gas_ptr;
typedef __attribute__((address_space(3))) u32* las_ptr;

#define QSCALE 0.18033688011112042f   // 0.125 * log2(e)

__device__ inline short f2bf(float x) {
    u32 u = __float_as_uint(x);
    u = u + 0x7FFFu + ((u >> 16) & 1u);   // RNE
    return (short)(u >> 16);
}
__device__ inline void gload16(const void* g, const void* l) {
    __builtin_amdgcn_global_load_lds((gas_ptr)g, (las_ptr)l, 16, 0, 0);
}

// ---------------------------------------------------------------------------
// prep: all fp32->bf16 converts + strata fold (transposed) + bc matvec.
// ---------------------------------------------------------------------------
__global__ __launch_bounds__(256) void prep(const float* __restrict__ X,
                                            const float* __restrict__ Wq,
                                            const float* __restrict__ Wk,
                                            const float* __restrict__ Wv,
                                            const float* __restrict__ Wo,
                                            const float* __restrict__ Ws,
                                            const float* __restrict__ bs,
                                            const float* __restrict__ bo,
                                            short* __restrict__ Xb,
                                            short* __restrict__ Wcat,
                                            short* __restrict__ Wob,
                                            short* __restrict__ WmT,
                                            float* __restrict__ bc) {
    __shared__ short T[64][65];
    const int tid = threadIdx.x;
    const int bid = blockIdx.x;
    if (bid < 8192) {
        const float* src;
        short* dst;
        int rel;
        if (bid < 4096)      { src = X;  dst = Xb;                rel = bid; }
        else if (bid < 5120) { src = Wq; dst = Wcat;              rel = bid - 4096; }
        else if (bid < 6144) { src = Wk; dst = Wcat + (1 << 20);  rel = bid - 5120; }
        else if (bid < 7168) { src = Wv; dst = Wcat + (2 << 20);  rel = bid - 6144; }
        else                 { src = Wo; dst = Wob;               rel = bid - 7168; }
        int i = (rel * 256 + tid) * 4;
        float4 v = *(const float4*)&src[i];
        short4v o;
        o[0] = f2bf(v.x); o[1] = f2bf(v.y); o[2] = f2bf(v.z); o[3] = f2bf(v.w);
        *(short4v*)&dst[i] = o;
    } else if (bid < 8448) {
        const int id = bid - 8192;
        const int gx = (id & 15) * 64, jy = (id >> 4) * 64;
        const int HH = 1 << 20;
        for (int e = tid; e < 4096; e += 256) {
            int j = e >> 6, g = e & 63;
            int idx = (jy + j) * 1024 + gx + g;
            float v = (Ws[idx] + Ws[idx + HH] + Ws[idx + 2 * HH]) * (1.0f / 3.0f);
            T[g][j] = f2bf(v);
        }
        __syncthreads();
        for (int e = tid; e < 4096; e += 256) {
            int g = e >> 6, j = e & 63;
            WmT[(long)(gx + g) * 1024 + jy + j] = T[g][j];
        }
    } else {
        const int lane = tid & 63;
        const int n = (bid - 8448) * 4 + (tid >> 6);
        float acc = 0.0f;
        for (int j0 = 0; j0 < 1024; j0 += 64) {
            int j = j0 + lane;
            float bm = (bs[j] + bs[j + 1024] + bs[j + 2048]) * (1.0f / 3.0f);
            acc += Wo[(long)n * 1024 + j] * bm;
        }
#pragma unroll
        for (int off = 1; off < 64; off <<= 1) acc += __shfl_xor(acc, off, 64);
        if (lane == 0) bc[n] = acc + bo[n];
    }
}

// ---------------------------------------------------------------------------
// Fused QKV + Wc GEMM, 128x128 tiles (m97 structure), BK=64, XOR-8 swizzle.
// 4 waves x 64x64 sub-tile, acc[4][4]. 832 blocks.
// Q pre-scaled by QSCALE; V stored transposed per-head.
// ---------------------------------------------------------------------------
__global__ __launch_bounds__(256) void gemm_qkvwc(const short* __restrict__ Xb,
                                                  const short* __restrict__ Wcat,
                                                  const short* __restrict__ Wob,
                                                  const short* __restrict__ WmT,
                                                  const float* __restrict__ bq,
                                                  const float* __restrict__ bk,
                                                  const float* __restrict__ bv,
                                                  short* __restrict__ Qb,
                                                  short* __restrict__ Kb,
                                                  short* __restrict__ Vt,
                                                  short* __restrict__ Wc) {
    __shared__ short As[128 * 64];
    __shared__ short Bs[128 * 64];
    const int K = 1024;
    const int tid  = threadIdx.x;
    const int lane = tid & 63;
    const int wave = tid >> 6;
    const int quad = lane >> 4;
    const int l16  = lane & 15;
    const int bid = blockIdx.x;
    const short *A, *W;
    int m0, n0, sel;
    if (bid < 768) {
        sel = bid >> 8;                 // 0..2 : Q,K,V
        int r = bid & 255;
        m0 = (r >> 3) * 128;            // 32 m-tiles
        n0 = (r & 7) * 128;             // 8 n-tiles
        A = Xb;
        W = Wcat + (long)sel * (1 << 20);
    } else {
        int w = bid - 768;              // 64 blocks: Wc = Wob @ WmT
        sel = 3;
        m0 = (w >> 3) * 128;
        n0 = (w & 7) * 128;
        A = Wob;
        W = WmT;
    }
    const int wm = (wave >> 1) * 64;
    const int wn = (wave & 1) * 64;

    f32x4 acc[4][4] = {};
    const int sr = tid >> 3;
    const int scol = (((tid & 7) ^ (sr & 7)) << 3);
    const int fo_a = ((quad ^ (l16 & 7)) << 3);
    const int fo_b = (((4 + quad) ^ (l16 & 7)) << 3);

    for (int k0 = 0; k0 < K; k0 += 64) {
#pragma unroll
        for (int i = 0; i < 4; i++) {
            int r = i * 32 + sr;
            gload16(&A[(long)(m0 + r) * K + k0 + scol], &As[i * 2048 + wave * 512]);
            gload16(&W[(long)(n0 + r) * K + k0 + scol], &Bs[i * 2048 + wave * 512]);
        }
        __syncthreads();
        short8 bfr[4][2];
#pragma unroll
        for (int ni = 0; ni < 4; ni++) {
            const int row = wn + ni * 16 + l16;
            bfr[ni][0] = *(short8*)&Bs[row * 64 + fo_a];
            bfr[ni][1] = *(short8*)&Bs[row * 64 + fo_b];
        }
#pragma unroll
        for (int mi = 0; mi < 4; mi++) {
            const int row = wm + mi * 16 + l16;
            short8 af0 = *(short8*)&As[row * 64 + fo_a];
            short8 af1 = *(short8*)&As[row * 64 + fo_b];
#pragma unroll
            for (int ni = 0; ni < 4; ni++) {
                acc[mi][ni] = __builtin_amdgcn_mfma_f32_16x16x32_bf16(af0, bfr[ni][0],
                                                                      acc[mi][ni], 0, 0, 0);
                acc[mi][ni] = __builtin_amdgcn_mfma_f32_16x16x32_bf16(af1, bfr[ni][1],
                                                                      acc[mi][ni], 0, 0, 0);
            }
        }
        __syncthreads();
    }

#pragma unroll
    for (int mi = 0; mi < 4; mi++) {
#pragma unroll
        for (int ni = 0; ni < 4; ni++) {
            const int n = n0 + wn + ni * 16 + l16;
            const int mbase = m0 + wm + mi * 16 + quad * 4;
            float bv2 = 0.0f;
            if (sel == 0) bv2 = bq[n];
            else if (sel == 1) bv2 = bk[n];
            else if (sel == 2) bv2 = bv[n];
            if (sel == 2) {
                short4v pk;
#pragma unroll
                for (int r = 0; r < 4; r++) pk[r] = f2bf(acc[mi][ni][r] + bv2);
                long addr = ((long)(mbase >> 11) << 21) + (long)n * 2048 + (mbase & 2047);
                *(short4v*)&Vt[addr] = pk;
            } else if (sel == 0) {
#pragma unroll
                for (int r = 0; r < 4; r++)
                    Qb[(long)(mbase + r) * 1024 + n] = f2bf((acc[mi][ni][r] + bv2) * QSCALE);
            } else {
                short* C = (sel == 1) ? Kb : Wc;
#pragma unroll
                for (int r = 0; r < 4; r++)
                    C[(long)(mbase + r) * 1024 + n] = f2bf(acc[mi][ni][r] + bv2);
            }
        }
    }
}

// ---------------------------------------------------------------------------
// Flash attention v4: 32x32x16 MFMA, block = 128 q x 8 waves (512 thr).
// Intra-block KV split: waves 0-3 -> kv [0,1024), waves 4-7 -> kv [1024,2048),
// each group double-buffers its own K and single-buffers its own V (48 KB LDS).
// P kept fully in registers: v_cvt_pk_bf16_f32 pairs + permlane32_swap build
// the PV B-fragments (no Ps LDS buffer, no pack/perm VALU chain).
// Partial (unnormalized O, lsum) merged through LDS at the end.
// grid (16 qt, 16 h, 2 b).
// ---------------------------------------------------------------------------
__global__ __launch_bounds__(512, 4) void attn_kernel(const short* __restrict__ Q,
                                                      const short* __restrict__ Kb,
                                                      const short* __restrict__ Vt,
                                                      short* __restrict__ O) {
    __shared__ short Ks[2][2][64 * 64];   // [group][buf] 32 KB
    __shared__ short Vs[2][64 * 64];      // [group]      16 KB
    const int tid   = threadIdx.x;
    const int lane  = tid & 63;
    const int wave  = tid >> 6;       // 0..7
    const int group = wave >> 2;      // kv half
    const int wv    = wave & 3;       // q sub-tile within block
    const int gtid  = tid & 255;      // id within group
    const int l32   = lane & 31;
    const int hi    = lane >> 5;
    const int sw    = l32 & 7;
    const int q0 = blockIdx.x * 128;
    const int h  = blockIdx.y;
    const int b  = blockIdx.z;

    // Q B-frags: B[k=d][n=q], lane: q=l32 (own row), d = t*16 + hi*8 + j
    short8 qB[4];
    {
        const long qbase = (long)(b * 2048 + q0 + wv * 32 + l32) * 1024 + h * 64 + hi * 8;
#pragma unroll
        for (int t = 0; t < 4; t++) qB[t] = *(const short8*)&Q[qbase + t * 16];
    }

    const int sr = gtid >> 3;                         // 0..31
    const int scol = (((gtid & 7) ^ (sr & 7)) << 3);
    const short* Kp = Kb + (long)(b * 2048 + group * 1024) * 1024 + h * 64;
    const short* Vp = Vt + ((long)b << 21) + (long)h * 64 * 2048 + group * 1024;

    f32x16 o[2] = {};
    float lsum = 0.0f;

    // prologue: stage K tile 0 of this group's half
#pragma unroll
    for (int i = 0; i < 2; i++) {
        int r = i * 32 + sr;
        gload16(&Kp[(long)r * 1024 + scol], &Ks[group][0][i * 2048 + wv * 512]);
    }
    __syncthreads();

    for (int kt = 0; kt < 16; kt++) {
        const int cur = kt & 1;
        const int kb = kt * 64;

        // stage V(kt) — group's waves done reading Vs at previous end barrier
#pragma unroll
        for (int i = 0; i < 2; i++) {
            int r = i * 32 + sr;
            gload16(&Vp[(long)r * 2048 + kb + scol], &Vs[group][i * 2048 + wv * 512]);
        }

        // S^T: two 32(kv) x 32(q) tiles; exp2 + in-register bf16 pack.
        // lane holds P[kv = kvt*32 + 8*c + 4*hi + r'][q = l32];
        // c0[c] = bf16 pair (r'=0,1), c1[c] = bf16 pair (r'=2,3), c = kvt*4+g.
        u32 c0[8], c1[8];
#pragma unroll
        for (int kvt = 0; kvt < 2; kvt++) {
            const int row = kvt * 32 + l32;
            f32x16 st = {};
#pragma unroll
            for (int step = 0; step < 4; step++) {
                short8 ak = *(short8*)&Ks[group][cur][row * 64 + (((step * 2 + hi) ^ sw) << 3)];
                st = __builtin_amdgcn_mfma_f32_32x32x16_bf16(ak, qB[step], st, 0, 0, 0);
            }
#pragma unroll
            for (int g = 0; g < 4; g++) {
                float p0 = __builtin_amdgcn_exp2f(st[g * 4 + 0]);
                float p1 = __builtin_amdgcn_exp2f(st[g * 4 + 1]);
                float p2 = __builtin_amdgcn_exp2f(st[g * 4 + 2]);
                float p3 = __builtin_amdgcn_exp2f(st[g * 4 + 3]);
                lsum += (p0 + p1) + (p2 + p3);
                u32 w0, w1;
                asm("v_cvt_pk_bf16_f32 %0, %1, %2" : "=v"(w0) : "v"(p0), "v"(p1));
                asm("v_cvt_pk_bf16_f32 %0, %1, %2" : "=v"(w1) : "v"(p2), "v"(p3));
                c0[kvt * 4 + g] = w0;
                c1[kvt * 4 + g] = w1;
            }
        }

        // mid barrier: V(kt) drained & visible; all K[cur] reads done
        __syncthreads();

        // prefetch K(kt+1) — drained at end barrier
        if (kt < 15) {
            const int kbn = kb + 64;
#pragma unroll
            for (int i = 0; i < 2; i++) {
                int r = i * 32 + sr;
                gload16(&Kp[(long)(kbn + r) * 1024 + scol],
                        &Ks[group][cur ^ 1][i * 2048 + wv * 512]);
            }
        }

        // Build P B-frags in-register: step s needs kv = s*16 + hi*8 + j.
        // permlane32_swap(vdst,vsrc): vdst.row1 <-> vsrc.row0, so
        // r[0] = {own c(2s) | partner c(2s+1)}, r[1] = {partner c(2s) | own c(2s+1)}.
        short8 pB[4];
#pragma unroll
        for (int s = 0; s < 4; s++) {
            u32x2 r0 = __builtin_amdgcn_permlane32_swap(c0[2 * s], c0[2 * s + 1], false, false);
            u32x2 r1 = __builtin_amdgcn_permlane32_swap(c1[2 * s], c1[2 * s + 1], false, false);
            u32x4 bw;
            bw[0] = r0[0]; bw[1] = r1[0]; bw[2] = r0[1]; bw[3] = r1[1];
            pB[s] = __builtin_bit_cast(short8, bw);
        }

        // O^T = V^T . P^T : two 32(d) x 32(q) tiles
#pragma unroll
        for (int dt = 0; dt < 2; dt++) {
            const int row = dt * 32 + l32;
#pragma unroll
            for (int s = 0; s < 4; s++) {
                short8 av = *(short8*)&Vs[group][row * 64 + (((s * 2 + hi) ^ sw) << 3)];
                o[dt] = __builtin_amdgcn_mfma_f32_32x32x16_bf16(av, pB[s], o[dt], 0, 0, 0);
            }
        }

        // end barrier: K(kt+1) drained; Vs reads done
        __syncthreads();
    }

    // merge the two kv halves through LDS (reuse Ks as f32 buffer, Vs for lsum)
    lsum += __shfl_xor(lsum, 32, 64);
    float* cb = (float*)&Ks[0][0][0];    // 128 q x 64 d f32 = 32 KB
    float* lb = (float*)&Vs[0][0];       // 128 f32
    const int ql = wv * 32 + l32;
    if (group == 1) {
#pragma unroll
        for (int dt = 0; dt < 2; dt++) {
#pragma unroll
            for (int g = 0; g < 4; g++) {
                f32x4 v4;
#pragma unroll
                for (int i = 0; i < 4; i++) v4[i] = o[dt][g * 4 + i];
                *(f32x4*)&cb[ql * 64 + dt * 32 + g * 8 + hi * 4] = v4;
            }
        }
        if (hi == 0) lb[ql] = lsum;
    }
    __syncthreads();
    if (group == 0) {
        const float inv = 1.0f / (lsum + lb[ql]);
        const long rbase = (long)(b * 2048 + q0 + ql) * 1024 + h * 64;
#pragma unroll
        for (int dt = 0; dt < 2; dt++) {
#pragma unroll
            for (int g = 0; g < 4; g++) {
                const f32x4 pv = *(const f32x4*)&cb[ql * 64 + dt * 32 + g * 8 + hi * 4];
                short4v pk;
#pragma unroll
                for (int i = 0; i < 4; i++) pk[i] = f2bf((o[dt][g * 4 + i] + pv[i]) * inv);
                *(short4v*)&O[rbase + dt * 32 + g * 8 + hi * 4] = pk;
            }
        }
    }
}

// ---------------------------------------------------------------------------
// Final GEMM: out = AO @ Wc^T + bc, fp32 out. 128x128 tiles, BK=64, swizzled.
// 256 blocks.
// ---------------------------------------------------------------------------
__global__ __launch_bounds__(256) void gemm_final(const short* __restrict__ A,
                                                  const short* __restrict__ W,
                                                  const float* __restrict__ bias,
                                                  float* __restrict__ C) {
    __shared__ short As[128 * 64];
    __shared__ short Bs[128 * 64];
    const int K = 1024;
    const int tid  = threadIdx.x;
    const int lane = tid & 63;
    const int wave = tid >> 6;
    const int quad = lane >> 4;
    const int l16  = lane & 15;
    const int bid = blockIdx.x;
    const int m0 = (bid >> 3) * 128;
    const int n0 = (bid & 7) * 128;
    const int wm = (wave >> 1) * 64;
    const int wn = (wave & 1) * 64;

    f32x4 acc[4][4] = {};
    const int sr = tid >> 3;
    const int scol = (((tid & 7) ^ (sr & 7)) << 3);
    const int fo_a = ((quad ^ (l16 & 7)) << 3);
    const int fo_b = (((4 + quad) ^ (l16 & 7)) << 3);

    for (int k0 = 0; k0 < K; k0 += 64) {
#pragma unroll
        for (int i = 0; i < 4; i++) {
            int r = i * 32 + sr;
            gload16(&A[(long)(m0 + r) * K + k0 + scol], &As[i * 2048 + wave * 512]);
            gload16(&W[(long)(n0 + r) * K + k0 + scol], &Bs[i * 2048 + wave * 512]);
        }
        __syncthreads();
        short8 bfr[4][2];
#pragma unroll
        for (int ni = 0; ni < 4; ni++) {
            const int row = wn + ni * 16 + l16;
            bfr[ni][0] = *(short8*)&Bs[row * 64 + fo_a];
            bfr[ni][1] = *(short8*)&Bs[row * 64 + fo_b];
        }
#pragma unroll
        for (int mi = 0; mi < 4; mi++) {
            const int row = wm + mi * 16 + l16;
            short8 af0 = *(short8*)&As[row * 64 + fo_a];
            short8 af1 = *(short8*)&As[row * 64 + fo_b];
#pragma unroll
            for (int ni = 0; ni < 4; ni++) {
                acc[mi][ni] = __builtin_amdgcn_mfma_f32_16x16x32_bf16(af0, bfr[ni][0],
                                                                      acc[mi][ni], 0, 0, 0);
                acc[mi][ni] = __builtin_amdgcn_mfma_f32_16x16x32_bf16(af1, bfr[ni][1],
                                                                      acc[mi][ni], 0, 0, 0);
            }
        }
        __syncthreads();
    }

#pragma unroll
    for (int mi = 0; mi < 4; mi++) {
#pragma unroll
        for (int ni = 0; ni < 4; ni++) {
            const int n = n0 + wn + ni * 16 + l16;
            const float bv = bias[n];
            const int mbase = m0 + wm + mi * 16 + quad * 4;
#pragma unroll
            for (int r = 0; r < 4; r++)
                C[(long)(mbase + r) * 1024 + n] = acc[mi][ni][r] + bv;
        }
    }
}

// ---------------------------------------------------------------------------
extern "C" void kernel_launch(void* const* d_in, const int* in_sizes, int n_in,
                              void* d_out, int out_size, void* d_ws, size_t ws_size,
                              hipStream_t stream) {
    const float* X  = (const float*)d_in[0];
    const float* Wq = (const float*)d_in[1];
    const float* bq = (const float*)d_in[2];
    const float* Wk = (const float*)d_in[3];
    const float* bk = (const float*)d_in[4];
    const float* Wv = (const float*)d_in[5];
    const float* bv = (const float*)d_in[6];
    const float* Ws = (const float*)d_in[7];
    const float* bs = (const float*)d_in[8];
    const float* Wo = (const float*)d_in[9];
    const float* bo = (const float*)d_in[10];

    char* ws = (char*)d_ws;
    const long MB = 1 << 20;
    short* Xb   = (short*)(ws + 0 * MB);   // 8 MB; reused as AO after QKV
    short* Wcat = (short*)(ws + 8 * MB);   // 6 MB (Wq,Wk,Wv bf16)
    short* WmT  = (short*)(ws + 14 * MB);  // 2 MB
    short* Wob  = (short*)(ws + 16 * MB);  // 2 MB
    short* Wc   = (short*)(ws + 18 * MB);  // 2 MB
    float* bc   = (float*)(ws + 20 * MB);  // 4 KB
    short* Qb   = (short*)(ws + 21 * MB);  // 8 MB
    short* Kbf  = (short*)(ws + 29 * MB);  // 8 MB
    short* Vtb  = (short*)(ws + 37 * MB);  // 8 MB
    short* AO   = Xb;

    dim3 bb(256);

    prep<<<dim3(8704), bb, 0, stream>>>(X, Wq, Wk, Wv, Wo, Ws, bs, bo,
                                        Xb, Wcat, Wob, WmT, bc);
    gemm_qkvwc<<<dim3(832), bb, 0, stream>>>(Xb, Wcat, Wob, WmT, bq, bk, bv,
                                             Qb, Kbf, Vtb, Wc);
    attn_kernel<<<dim3(16, 16, 2), dim3(512), 0, stream>>>(Qb, Kbf, Vtb, AO);
    gemm_final<<<dim3(256), bb, 0, stream>>>(AO, Wc, bc, (float*)d_out);
}

// Round 3
// 210.960 us; speedup vs baseline: 1.0979x; 1.0979x over previous
//
#include <hip/hip_runtime.h>
#include <stdint.h>

typedef __attribute__((ext_vector_type(8))) short short8;
typedef __attribute__((ext_vector_type(4))) short short4v;
typedef __attribute__((ext_vector_type(4))) float f32x4;
typedef __attribute__((ext_vector_type(16))) float f32x16;
typedef __attribute__((ext_vector_type(2))) unsigned int u32x2;
typedef __attribute__((ext_vector_type(4))) unsigned int u32x4;
typedef unsigned int u32;
typedef const __attribute__((address_space(1))) u32* gas_ptr;
typedef __attribute__((address_space(3))) u32* las_ptr;

#define QSCALE 0.18033688011112042f   // 0.125 * log2(e)

__device__ inline short f2bf(float x) {
    u32 u = __float_as_uint(x);
    u = u + 0x7FFFu + ((u >> 16) & 1u);   // RNE
    return (short)(u >> 16);
}
__device__ inline void gload16(const void* g, const void* l) {
    __builtin_amdgcn_global_load_lds((gas_ptr)g, (las_ptr)l, 16, 0, 0);
}

// ---------------------------------------------------------------------------
// prep: all fp32->bf16 converts + strata fold (transposed) + bc matvec.
// Part 1 grid-strided 4x (2048 blocks instead of 8192) to cut dispatch count.
// ---------------------------------------------------------------------------
__global__ __launch_bounds__(256) void prep(const float* __restrict__ X,
                                            const float* __restrict__ Wq,
                                            const float* __restrict__ Wk,
                                            const float* __restrict__ Wv,
                                            const float* __restrict__ Wo,
                                            const float* __restrict__ Ws,
                                            const float* __restrict__ bs,
                                            const float* __restrict__ bo,
                                            short* __restrict__ Xb,
                                            short* __restrict__ Wcat,
                                            short* __restrict__ Wob,
                                            short* __restrict__ WmT,
                                            float* __restrict__ bc) {
    __shared__ short T[64][65];
    const int tid = threadIdx.x;
    const int bid = blockIdx.x;
    if (bid < 2048) {
#pragma unroll
        for (int c = 0; c < 4; c++) {
            const int chunk = bid * 4 + c;
            const float* src;
            short* dst;
            int rel;
            if (chunk < 4096)      { src = X;  dst = Xb;                rel = chunk; }
            else if (chunk < 5120) { src = Wq; dst = Wcat;              rel = chunk - 4096; }
            else if (chunk < 6144) { src = Wk; dst = Wcat + (1 << 20);  rel = chunk - 5120; }
            else if (chunk < 7168) { src = Wv; dst = Wcat + (2 << 20);  rel = chunk - 6144; }
            else                   { src = Wo; dst = Wob;               rel = chunk - 7168; }
            int i = (rel * 256 + tid) * 4;
            float4 v = *(const float4*)&src[i];
            short4v o;
            o[0] = f2bf(v.x); o[1] = f2bf(v.y); o[2] = f2bf(v.z); o[3] = f2bf(v.w);
            *(short4v*)&dst[i] = o;
        }
    } else if (bid < 2304) {
        const int id = bid - 2048;
        const int gx = (id & 15) * 64, jy = (id >> 4) * 64;
        const int HH = 1 << 20;
        for (int e = tid; e < 4096; e += 256) {
            int j = e >> 6, g = e & 63;
            int idx = (jy + j) * 1024 + gx + g;
            float v = (Ws[idx] + Ws[idx + HH] + Ws[idx + 2 * HH]) * (1.0f / 3.0f);
            T[g][j] = f2bf(v);
        }
        __syncthreads();
        for (int e = tid; e < 4096; e += 256) {
            int g = e >> 6, j = e & 63;
            WmT[(long)(gx + g) * 1024 + jy + j] = T[g][j];
        }
    } else {
        const int lane = tid & 63;
        const int n = (bid - 2304) * 4 + (tid >> 6);
        float acc = 0.0f;
        for (int j0 = 0; j0 < 1024; j0 += 64) {
            int j = j0 + lane;
            float bm = (bs[j] + bs[j + 1024] + bs[j + 2048]) * (1.0f / 3.0f);
            acc += Wo[(long)n * 1024 + j] * bm;
        }
#pragma unroll
        for (int off = 1; off < 64; off <<= 1) acc += __shfl_xor(acc, off, 64);
        if (lane == 0) bc[n] = acc + bo[n];
    }
}

// ---------------------------------------------------------------------------
// Fused QKV + Wc GEMM, 64x128 tiles, BK=64, XOR-8 swizzled LDS. 1664 blocks.
// (128x128 regressed: acc[4][4]+112 VGPR -> 2 blocks/CU, occupancy 16%.)
// Q pre-scaled by QSCALE; V stored transposed per-head.
// ---------------------------------------------------------------------------
__global__ __launch_bounds__(256) void gemm_qkvwc(const short* __restrict__ Xb,
                                                  const short* __restrict__ Wcat,
                                                  const short* __restrict__ Wob,
                                                  const short* __restrict__ WmT,
                                                  const float* __restrict__ bq,
                                                  const float* __restrict__ bk,
                                                  const float* __restrict__ bv,
                                                  short* __restrict__ Qb,
                                                  short* __restrict__ Kb,
                                                  short* __restrict__ Vt,
                                                  short* __restrict__ Wc) {
    __shared__ short As[64 * 64];
    __shared__ short Bs[128 * 64];
    const int K = 1024;
    const int tid  = threadIdx.x;
    const int lane = tid & 63;
    const int wave = tid >> 6;
    const int quad = lane >> 4;
    const int l16  = lane & 15;
    const int bid = blockIdx.x;
    const short *A, *W;
    int m0, n0, sel;
    if (bid < 1536) {
        sel = bid >> 9;
        int r = bid & 511;
        m0 = (r >> 3) * 64;
        n0 = (r & 7) * 128;
        A = Xb;
        W = Wcat + (long)sel * (1 << 20);
    } else {
        int w = bid - 1536;
        sel = 3;
        m0 = (w >> 3) * 64;
        n0 = (w & 7) * 128;
        A = Wob;
        W = WmT;
    }
    const int wm = (wave >> 1) * 32;
    const int wn = (wave & 1) * 64;

    f32x4 acc[2][4] = {};
    const int sr = tid >> 3;
    const int scol = (((tid & 7) ^ (sr & 7)) << 3);
    const int fo_a = ((quad ^ (l16 & 7)) << 3);
    const int fo_b = (((4 + quad) ^ (l16 & 7)) << 3);

    for (int k0 = 0; k0 < K; k0 += 64) {
#pragma unroll
        for (int i = 0; i < 2; i++) {
            int r = i * 32 + sr;
            gload16(&A[(long)(m0 + r) * K + k0 + scol], &As[i * 2048 + wave * 512]);
        }
#pragma unroll
        for (int i = 0; i < 4; i++) {
            int r = i * 32 + sr;
            gload16(&W[(long)(n0 + r) * K + k0 + scol], &Bs[i * 2048 + wave * 512]);
        }
        __syncthreads();
        short8 bfr[4][2];
#pragma unroll
        for (int ni = 0; ni < 4; ni++) {
            const int row = wn + ni * 16 + l16;
            bfr[ni][0] = *(short8*)&Bs[row * 64 + fo_a];
            bfr[ni][1] = *(short8*)&Bs[row * 64 + fo_b];
        }
#pragma unroll
        for (int mi = 0; mi < 2; mi++) {
            const int row = wm + mi * 16 + l16;
            short8 af0 = *(short8*)&As[row * 64 + fo_a];
            short8 af1 = *(short8*)&As[row * 64 + fo_b];
#pragma unroll
            for (int ni = 0; ni < 4; ni++) {
                acc[mi][ni] = __builtin_amdgcn_mfma_f32_16x16x32_bf16(af0, bfr[ni][0],
                                                                      acc[mi][ni], 0, 0, 0);
                acc[mi][ni] = __builtin_amdgcn_mfma_f32_16x16x32_bf16(af1, bfr[ni][1],
                                                                      acc[mi][ni], 0, 0, 0);
            }
        }
        __syncthreads();
    }

#pragma unroll
    for (int mi = 0; mi < 2; mi++) {
#pragma unroll
        for (int ni = 0; ni < 4; ni++) {
            const int n = n0 + wn + ni * 16 + l16;
            const int mbase = m0 + wm + mi * 16 + quad * 4;
            float bv2 = 0.0f;
            if (sel == 0) bv2 = bq[n];
            else if (sel == 1) bv2 = bk[n];
            else if (sel == 2) bv2 = bv[n];
            if (sel == 2) {
                short4v pk;
#pragma unroll
                for (int r = 0; r < 4; r++) pk[r] = f2bf(acc[mi][ni][r] + bv2);
                long addr = ((long)(mbase >> 11) << 21) + (long)n * 2048 + (mbase & 2047);
                *(short4v*)&Vt[addr] = pk;
            } else if (sel == 0) {
#pragma unroll
                for (int r = 0; r < 4; r++)
                    Qb[(long)(mbase + r) * 1024 + n] = f2bf((acc[mi][ni][r] + bv2) * QSCALE);
            } else {
                short* C = (sel == 1) ? Kb : Wc;
#pragma unroll
                for (int r = 0; r < 4; r++)
                    C[(long)(mbase + r) * 1024 + n] = f2bf(acc[mi][ni][r] + bv2);
            }
        }
    }
}

// ---------------------------------------------------------------------------
// Flash attention v4 + T5 setprio: 32x32x16 MFMA, block = 128 q x 8 waves.
// Intra-block KV split: waves 0-3 -> kv [0,1024), waves 4-7 -> kv [1024,2048),
// each group double-buffers its own K and single-buffers its own V (48 KB LDS).
// P kept fully in registers via v_cvt_pk_bf16_f32 + permlane32_swap.
// grid (16 qt, 16 h, 2 b).
// ---------------------------------------------------------------------------
__global__ __launch_bounds__(512, 4) void attn_kernel(const short* __restrict__ Q,
                                                      const short* __restrict__ Kb,
                                                      const short* __restrict__ Vt,
                                                      short* __restrict__ O) {
    __shared__ short Ks[2][2][64 * 64];   // [group][buf] 32 KB
    __shared__ short Vs[2][64 * 64];      // [group]      16 KB
    const int tid   = threadIdx.x;
    const int lane  = tid & 63;
    const int wave  = tid >> 6;       // 0..7
    const int group = wave >> 2;      // kv half
    const int wv    = wave & 3;       // q sub-tile within block
    const int gtid  = tid & 255;      // id within group
    const int l32   = lane & 31;
    const int hi    = lane >> 5;
    const int sw    = l32 & 7;
    const int q0 = blockIdx.x * 128;
    const int h  = blockIdx.y;
    const int b  = blockIdx.z;

    // Q B-frags: B[k=d][n=q], lane: q=l32 (own row), d = t*16 + hi*8 + j
    short8 qB[4];
    {
        const long qbase = (long)(b * 2048 + q0 + wv * 32 + l32) * 1024 + h * 64 + hi * 8;
#pragma unroll
        for (int t = 0; t < 4; t++) qB[t] = *(const short8*)&Q[qbase + t * 16];
    }

    const int sr = gtid >> 3;                         // 0..31
    const int scol = (((gtid & 7) ^ (sr & 7)) << 3);
    const short* Kp = Kb + (long)(b * 2048 + group * 1024) * 1024 + h * 64;
    const short* Vp = Vt + ((long)b << 21) + (long)h * 64 * 2048 + group * 1024;

    f32x16 o[2] = {};
    float lsum = 0.0f;

    // prologue: stage K tile 0 of this group's half
#pragma unroll
    for (int i = 0; i < 2; i++) {
        int r = i * 32 + sr;
        gload16(&Kp[(long)r * 1024 + scol], &Ks[group][0][i * 2048 + wv * 512]);
    }
    __syncthreads();

    for (int kt = 0; kt < 16; kt++) {
        const int cur = kt & 1;
        const int kb = kt * 64;

        // stage V(kt) — group's waves done reading Vs at previous end barrier
#pragma unroll
        for (int i = 0; i < 2; i++) {
            int r = i * 32 + sr;
            gload16(&Vp[(long)r * 2048 + kb + scol], &Vs[group][i * 2048 + wv * 512]);
        }

        // S^T: two 32(kv) x 32(q) tiles; exp2 + in-register bf16 pack.
        // lane holds P[kv = kvt*32 + 8*c + 4*hi + r'][q = l32];
        // c0[c] = bf16 pair (r'=0,1), c1[c] = bf16 pair (r'=2,3), c = kvt*4+g.
        u32 c0[8], c1[8];
#pragma unroll
        for (int kvt = 0; kvt < 2; kvt++) {
            const int row = kvt * 32 + l32;
            f32x16 st = {};
            __builtin_amdgcn_s_setprio(1);
#pragma unroll
            for (int step = 0; step < 4; step++) {
                short8 ak = *(short8*)&Ks[group][cur][row * 64 + (((step * 2 + hi) ^ sw) << 3)];
                st = __builtin_amdgcn_mfma_f32_32x32x16_bf16(ak, qB[step], st, 0, 0, 0);
            }
            __builtin_amdgcn_s_setprio(0);
#pragma unroll
            for (int g = 0; g < 4; g++) {
                float p0 = __builtin_amdgcn_exp2f(st[g * 4 + 0]);
                float p1 = __builtin_amdgcn_exp2f(st[g * 4 + 1]);
                float p2 = __builtin_amdgcn_exp2f(st[g * 4 + 2]);
                float p3 = __builtin_amdgcn_exp2f(st[g * 4 + 3]);
                lsum += (p0 + p1) + (p2 + p3);
                u32 w0, w1;
                asm("v_cvt_pk_bf16_f32 %0, %1, %2" : "=v"(w0) : "v"(p0), "v"(p1));
                asm("v_cvt_pk_bf16_f32 %0, %1, %2" : "=v"(w1) : "v"(p2), "v"(p3));
                c0[kvt * 4 + g] = w0;
                c1[kvt * 4 + g] = w1;
            }
        }

        // mid barrier: V(kt) drained & visible; all K[cur] reads done
        __syncthreads();

        // prefetch K(kt+1) — drained at end barrier
        if (kt < 15) {
            const int kbn = kb + 64;
#pragma unroll
            for (int i = 0; i < 2; i++) {
                int r = i * 32 + sr;
                gload16(&Kp[(long)(kbn + r) * 1024 + scol],
                        &Ks[group][cur ^ 1][i * 2048 + wv * 512]);
            }
        }

        // Build P B-frags in-register: step s needs kv = s*16 + hi*8 + j.
        // permlane32_swap(vdst,vsrc): vdst.row1 <-> vsrc.row0, so
        // r[0] = {own c(2s) | partner c(2s+1)}, r[1] = {partner c(2s) | own c(2s+1)}.
        short8 pB[4];
#pragma unroll
        for (int s = 0; s < 4; s++) {
            u32x2 r0 = __builtin_amdgcn_permlane32_swap(c0[2 * s], c0[2 * s + 1], false, false);
            u32x2 r1 = __builtin_amdgcn_permlane32_swap(c1[2 * s], c1[2 * s + 1], false, false);
            u32x4 bw;
            bw[0] = r0[0]; bw[1] = r1[0]; bw[2] = r0[1]; bw[3] = r1[1];
            pB[s] = __builtin_bit_cast(short8, bw);
        }

        // O^T = V^T . P^T : two 32(d) x 32(q) tiles
        __builtin_amdgcn_s_setprio(1);
#pragma unroll
        for (int dt = 0; dt < 2; dt++) {
            const int row = dt * 32 + l32;
#pragma unroll
            for (int s = 0; s < 4; s++) {
                short8 av = *(short8*)&Vs[group][row * 64 + (((s * 2 + hi) ^ sw) << 3)];
                o[dt] = __builtin_amdgcn_mfma_f32_32x32x16_bf16(av, pB[s], o[dt], 0, 0, 0);
            }
        }
        __builtin_amdgcn_s_setprio(0);

        // end barrier: K(kt+1) drained; Vs reads done
        __syncthreads();
    }

    // merge the two kv halves through LDS (reuse Ks as f32 buffer, Vs for lsum)
    lsum += __shfl_xor(lsum, 32, 64);
    float* cb = (float*)&Ks[0][0][0];    // 128 q x 64 d f32 = 32 KB
    float* lb = (float*)&Vs[0][0];       // 128 f32
    const int ql = wv * 32 + l32;
    if (group == 1) {
#pragma unroll
        for (int dt = 0; dt < 2; dt++) {
#pragma unroll
            for (int g = 0; g < 4; g++) {
                f32x4 v4;
#pragma unroll
                for (int i = 0; i < 4; i++) v4[i] = o[dt][g * 4 + i];
                *(f32x4*)&cb[ql * 64 + dt * 32 + g * 8 + hi * 4] = v4;
            }
        }
        if (hi == 0) lb[ql] = lsum;
    }
    __syncthreads();
    if (group == 0) {
        const float inv = 1.0f / (lsum + lb[ql]);
        const long rbase = (long)(b * 2048 + q0 + ql) * 1024 + h * 64;
#pragma unroll
        for (int dt = 0; dt < 2; dt++) {
#pragma unroll
            for (int g = 0; g < 4; g++) {
                const f32x4 pv = *(const f32x4*)&cb[ql * 64 + dt * 32 + g * 8 + hi * 4];
                short4v pk;
#pragma unroll
                for (int i = 0; i < 4; i++) pk[i] = f2bf((o[dt][g * 4 + i] + pv[i]) * inv);
                *(short4v*)&O[rbase + dt * 32 + g * 8 + hi * 4] = pk;
            }
        }
    }
}

// ---------------------------------------------------------------------------
// Final GEMM: out = AO @ Wc^T + bc, fp32 out. 64x128 tiles, BK=64, swizzled.
// 512 blocks.
// ---------------------------------------------------------------------------
__global__ __launch_bounds__(256) void gemm_final(const short* __restrict__ A,
                                                  const short* __restrict__ W,
                                                  const float* __restrict__ bias,
                                                  float* __restrict__ C) {
    __shared__ short As[64 * 64];
    __shared__ short Bs[128 * 64];
    const int K = 1024;
    const int tid  = threadIdx.x;
    const int lane = tid & 63;
    const int wave = tid >> 6;
    const int quad = lane >> 4;
    const int l16  = lane & 15;
    const int bid = blockIdx.x;
    const int m0 = (bid >> 3) * 64;
    const int n0 = (bid & 7) * 128;
    const int wm = (wave >> 1) * 32;
    const int wn = (wave & 1) * 64;

    f32x4 acc[2][4] = {};
    const int sr = tid >> 3;
    const int scol = (((tid & 7) ^ (sr & 7)) << 3);
    const int fo_a = ((quad ^ (l16 & 7)) << 3);
    const int fo_b = (((4 + quad) ^ (l16 & 7)) << 3);

    for (int k0 = 0; k0 < K; k0 += 64) {
#pragma unroll
        for (int i = 0; i < 2; i++) {
            int r = i * 32 + sr;
            gload16(&A[(long)(m0 + r) * K + k0 + scol], &As[i * 2048 + wave * 512]);
        }
#pragma unroll
        for (int i = 0; i < 4; i++) {
            int r = i * 32 + sr;
            gload16(&W[(long)(n0 + r) * K + k0 + scol], &Bs[i * 2048 + wave * 512]);
        }
        __syncthreads();
        short8 bfr[4][2];
#pragma unroll
        for (int ni = 0; ni < 4; ni++) {
            const int row = wn + ni * 16 + l16;
            bfr[ni][0] = *(short8*)&Bs[row * 64 + fo_a];
            bfr[ni][1] = *(short8*)&Bs[row * 64 + fo_b];
        }
#pragma unroll
        for (int mi = 0; mi < 2; mi++) {
            const int row = wm + mi * 16 + l16;
            short8 af0 = *(short8*)&As[row * 64 + fo_a];
            short8 af1 = *(short8*)&As[row * 64 + fo_b];
#pragma unroll
            for (int ni = 0; ni < 4; ni++) {
                acc[mi][ni] = __builtin_amdgcn_mfma_f32_16x16x32_bf16(af0, bfr[ni][0],
                                                                      acc[mi][ni], 0, 0, 0);
                acc[mi][ni] = __builtin_amdgcn_mfma_f32_16x16x32_bf16(af1, bfr[ni][1],
                                                                      acc[mi][ni], 0, 0, 0);
            }
        }
        __syncthreads();
    }

#pragma unroll
    for (int mi = 0; mi < 2; mi++) {
#pragma unroll
        for (int ni = 0; ni < 4; ni++) {
            const int n = n0 + wn + ni * 16 + l16;
            const float bv = bias[n];
            const int mbase = m0 + wm + mi * 16 + quad * 4;
#pragma unroll
            for (int r = 0; r < 4; r++)
                C[(long)(mbase + r) * 1024 + n] = acc[mi][ni][r] + bv;
        }
    }
}

// ---------------------------------------------------------------------------
extern "C" void kernel_launch(void* const* d_in, const int* in_sizes, int n_in,
                              void* d_out, int out_size, void* d_ws, size_t ws_size,
                              hipStream_t stream) {
    const float* X  = (const float*)d_in[0];
    const float* Wq = (const float*)d_in[1];
    const float* bq = (const float*)d_in[2];
    const float* Wk = (const float*)d_in[3];
    const float* bk = (const float*)d_in[4];
    const float* Wv = (const float*)d_in[5];
    const float* bv = (const float*)d_in[6];
    const float* Ws = (const float*)d_in[7];
    const float* bs = (const float*)d_in[8];
    const float* Wo = (const float*)d_in[9];
    const float* bo = (const float*)d_in[10];

    char* ws = (char*)d_ws;
    const long MB = 1 << 20;
    short* Xb   = (short*)(ws + 0 * MB);   // 8 MB; reused as AO after QKV
    short* Wcat = (short*)(ws + 8 * MB);   // 6 MB (Wq,Wk,Wv bf16)
    short* WmT  = (short*)(ws + 14 * MB);  // 2 MB
    short* Wob  = (short*)(ws + 16 * MB);  // 2 MB
    short* Wc   = (short*)(ws + 18 * MB);  // 2 MB
    float* bc   = (float*)(ws + 20 * MB);  // 4 KB
    short* Qb   = (short*)(ws + 21 * MB);  // 8 MB
    short* Kbf  = (short*)(ws + 29 * MB);  // 8 MB
    short* Vtb  = (short*)(ws + 37 * MB);  // 8 MB
    short* AO   = Xb;

    dim3 bb(256);

    prep<<<dim3(2560), bb, 0, stream>>>(X, Wq, Wk, Wv, Wo, Ws, bs, bo,
                                        Xb, Wcat, Wob, WmT, bc);
    gemm_qkvwc<<<dim3(1664), bb, 0, stream>>>(Xb, Wcat, Wob, WmT, bq, bk, bv,
                                              Qb, Kbf, Vtb, Wc);
    attn_kernel<<<dim3(16, 16, 2), dim3(512), 0, stream>>>(Qb, Kbf, Vtb, AO);
    gemm_final<<<dim3(512), bb, 0, stream>>>(AO, Wc, bc, (float*)d_out);
}

// Round 4
// 209.763 us; speedup vs baseline: 1.1042x; 1.0057x over previous
//
#include <hip/hip_runtime.h>
#include <stdint.h>

typedef __attribute__((ext_vector_type(8))) short short8;
typedef __attribute__((ext_vector_type(4))) short short4v;
typedef __attribute__((ext_vector_type(4))) float f32x4;
typedef __attribute__((ext_vector_type(16))) float f32x16;
typedef __attribute__((ext_vector_type(2))) unsigned int u32x2;
typedef __attribute__((ext_vector_type(4))) unsigned int u32x4;
typedef unsigned int u32;
typedef const __attribute__((address_space(1))) u32* gas_ptr;
typedef __attribute__((address_space(3))) u32* las_ptr;

#define QSCALE 0.18033688011112042f   // 0.125 * log2(e)

__device__ inline short f2bf(float x) {
    u32 u = __float_as_uint(x);
    u = u + 0x7FFFu + ((u >> 16) & 1u);   // RNE
    return (short)(u >> 16);
}
__device__ inline void gload16(const void* g, const void* l) {
    __builtin_amdgcn_global_load_lds((gas_ptr)g, (las_ptr)l, 16, 0, 0);
}

// ---------------------------------------------------------------------------
// prep: all fp32->bf16 converts + strata fold (transposed) + bc matvec.
// ---------------------------------------------------------------------------
__global__ __launch_bounds__(256) void prep(const float* __restrict__ X,
                                            const float* __restrict__ Wq,
                                            const float* __restrict__ Wk,
                                            const float* __restrict__ Wv,
                                            const float* __restrict__ Wo,
                                            const float* __restrict__ Ws,
                                            const float* __restrict__ bs,
                                            const float* __restrict__ bo,
                                            short* __restrict__ Xb,
                                            short* __restrict__ Wcat,
                                            short* __restrict__ Wob,
                                            short* __restrict__ WmT,
                                            float* __restrict__ bc) {
    __shared__ short T[64][65];
    const int tid = threadIdx.x;
    const int bid = blockIdx.x;
    if (bid < 2048) {
#pragma unroll
        for (int c = 0; c < 4; c++) {
            const int chunk = bid * 4 + c;
            const float* src;
            short* dst;
            int rel;
            if (chunk < 4096)      { src = X;  dst = Xb;                rel = chunk; }
            else if (chunk < 5120) { src = Wq; dst = Wcat;              rel = chunk - 4096; }
            else if (chunk < 6144) { src = Wk; dst = Wcat + (1 << 20);  rel = chunk - 5120; }
            else if (chunk < 7168) { src = Wv; dst = Wcat + (2 << 20);  rel = chunk - 6144; }
            else                   { src = Wo; dst = Wob;               rel = chunk - 7168; }
            int i = (rel * 256 + tid) * 4;
            float4 v = *(const float4*)&src[i];
            short4v o;
            o[0] = f2bf(v.x); o[1] = f2bf(v.y); o[2] = f2bf(v.z); o[3] = f2bf(v.w);
            *(short4v*)&dst[i] = o;
        }
    } else if (bid < 2304) {
        const int id = bid - 2048;
        const int gx = (id & 15) * 64, jy = (id >> 4) * 64;
        const int HH = 1 << 20;
        for (int e = tid; e < 4096; e += 256) {
            int j = e >> 6, g = e & 63;
            int idx = (jy + j) * 1024 + gx + g;
            float v = (Ws[idx] + Ws[idx + HH] + Ws[idx + 2 * HH]) * (1.0f / 3.0f);
            T[g][j] = f2bf(v);
        }
        __syncthreads();
        for (int e = tid; e < 4096; e += 256) {
            int g = e >> 6, j = e & 63;
            WmT[(long)(gx + g) * 1024 + jy + j] = T[g][j];
        }
    } else {
        const int lane = tid & 63;
        const int n = (bid - 2304) * 4 + (tid >> 6);
        float acc = 0.0f;
        for (int j0 = 0; j0 < 1024; j0 += 64) {
            int j = j0 + lane;
            float bm = (bs[j] + bs[j + 1024] + bs[j + 2048]) * (1.0f / 3.0f);
            acc += Wo[(long)n * 1024 + j] * bm;
        }
#pragma unroll
        for (int off = 1; off < 64; off <<= 1) acc += __shfl_xor(acc, off, 64);
        if (lane == 0) bc[n] = acc + bo[n];
    }
}

// ---------------------------------------------------------------------------
// Fused QKV + Wc GEMM, 64x128 tiles, BK=128 (two 64-sub-tiles per barrier
// pair -> 8 barrier drains instead of 16). XOR-8 swizzled LDS. 1664 blocks.
// Q pre-scaled by QSCALE; V stored transposed per-head.
// ---------------------------------------------------------------------------
__global__ __launch_bounds__(256) void gemm_qkvwc(const short* __restrict__ Xb,
                                                  const short* __restrict__ Wcat,
                                                  const short* __restrict__ Wob,
                                                  const short* __restrict__ WmT,
                                                  const float* __restrict__ bq,
                                                  const float* __restrict__ bk,
                                                  const float* __restrict__ bv,
                                                  short* __restrict__ Qb,
                                                  short* __restrict__ Kb,
                                                  short* __restrict__ Vt,
                                                  short* __restrict__ Wc) {
    __shared__ short As[2][64 * 64];
    __shared__ short Bs[2][128 * 64];
    const int K = 1024;
    const int tid  = threadIdx.x;
    const int lane = tid & 63;
    const int wave = tid >> 6;
    const int quad = lane >> 4;
    const int l16  = lane & 15;
    const int bid = blockIdx.x;
    const short *A, *W;
    int m0, n0, sel;
    if (bid < 1536) {
        sel = bid >> 9;
        int r = bid & 511;
        m0 = (r >> 3) * 64;
        n0 = (r & 7) * 128;
        A = Xb;
        W = Wcat + (long)sel * (1 << 20);
    } else {
        int w = bid - 1536;
        sel = 3;
        m0 = (w >> 3) * 64;
        n0 = (w & 7) * 128;
        A = Wob;
        W = WmT;
    }
    const int wm = (wave >> 1) * 32;
    const int wn = (wave & 1) * 64;

    f32x4 acc[2][4] = {};
    const int sr = tid >> 3;
    const int scol = (((tid & 7) ^ (sr & 7)) << 3);
    const int fo_a = ((quad ^ (l16 & 7)) << 3);
    const int fo_b = (((4 + quad) ^ (l16 & 7)) << 3);

    for (int k0 = 0; k0 < K; k0 += 128) {
#pragma unroll
        for (int half = 0; half < 2; half++) {
            const int kk = k0 + half * 64;
#pragma unroll
            for (int i = 0; i < 2; i++) {
                int r = i * 32 + sr;
                gload16(&A[(long)(m0 + r) * K + kk + scol], &As[half][i * 2048 + wave * 512]);
            }
#pragma unroll
            for (int i = 0; i < 4; i++) {
                int r = i * 32 + sr;
                gload16(&W[(long)(n0 + r) * K + kk + scol], &Bs[half][i * 2048 + wave * 512]);
            }
        }
        __syncthreads();
#pragma unroll
        for (int half = 0; half < 2; half++) {
            short8 bfr[4][2];
#pragma unroll
            for (int ni = 0; ni < 4; ni++) {
                const int row = wn + ni * 16 + l16;
                bfr[ni][0] = *(short8*)&Bs[half][row * 64 + fo_a];
                bfr[ni][1] = *(short8*)&Bs[half][row * 64 + fo_b];
            }
#pragma unroll
            for (int mi = 0; mi < 2; mi++) {
                const int row = wm + mi * 16 + l16;
                short8 af0 = *(short8*)&As[half][row * 64 + fo_a];
                short8 af1 = *(short8*)&As[half][row * 64 + fo_b];
#pragma unroll
                for (int ni = 0; ni < 4; ni++) {
                    acc[mi][ni] = __builtin_amdgcn_mfma_f32_16x16x32_bf16(af0, bfr[ni][0],
                                                                          acc[mi][ni], 0, 0, 0);
                    acc[mi][ni] = __builtin_amdgcn_mfma_f32_16x16x32_bf16(af1, bfr[ni][1],
                                                                          acc[mi][ni], 0, 0, 0);
                }
            }
        }
        __syncthreads();
    }

#pragma unroll
    for (int mi = 0; mi < 2; mi++) {
#pragma unroll
        for (int ni = 0; ni < 4; ni++) {
            const int n = n0 + wn + ni * 16 + l16;
            const int mbase = m0 + wm + mi * 16 + quad * 4;
            float bv2 = 0.0f;
            if (sel == 0) bv2 = bq[n];
            else if (sel == 1) bv2 = bk[n];
            else if (sel == 2) bv2 = bv[n];
            if (sel == 2) {
                short4v pk;
#pragma unroll
                for (int r = 0; r < 4; r++) pk[r] = f2bf(acc[mi][ni][r] + bv2);
                long addr = ((long)(mbase >> 11) << 21) + (long)n * 2048 + (mbase & 2047);
                *(short4v*)&Vt[addr] = pk;
            } else if (sel == 0) {
#pragma unroll
                for (int r = 0; r < 4; r++)
                    Qb[(long)(mbase + r) * 1024 + n] = f2bf((acc[mi][ni][r] + bv2) * QSCALE);
            } else {
                short* C = (sel == 1) ? Kb : Wc;
#pragma unroll
                for (int r = 0; r < 4; r++)
                    C[(long)(mbase + r) * 1024 + n] = f2bf(acc[mi][ni][r] + bv2);
            }
        }
    }
}

// ---------------------------------------------------------------------------
// Flash attention v4 + T5 setprio: 32x32x16 MFMA, block = 128 q x 8 waves.
// Intra-block KV split: waves 0-3 -> kv [0,1024), waves 4-7 -> kv [1024,2048),
// each group double-buffers its own K and single-buffers its own V (48 KB LDS).
// P kept fully in registers via v_cvt_pk_bf16_f32 + permlane32_swap.
// grid (16 qt, 16 h, 2 b).
// ---------------------------------------------------------------------------
__global__ __launch_bounds__(512, 4) void attn_kernel(const short* __restrict__ Q,
                                                      const short* __restrict__ Kb,
                                                      const short* __restrict__ Vt,
                                                      short* __restrict__ O) {
    __shared__ short Ks[2][2][64 * 64];   // [group][buf] 32 KB
    __shared__ short Vs[2][64 * 64];      // [group]      16 KB
    const int tid   = threadIdx.x;
    const int lane  = tid & 63;
    const int wave  = tid >> 6;       // 0..7
    const int group = wave >> 2;      // kv half
    const int wv    = wave & 3;       // q sub-tile within block
    const int gtid  = tid & 255;      // id within group
    const int l32   = lane & 31;
    const int hi    = lane >> 5;
    const int sw    = l32 & 7;
    const int q0 = blockIdx.x * 128;
    const int h  = blockIdx.y;
    const int b  = blockIdx.z;

    // Q B-frags: B[k=d][n=q], lane: q=l32 (own row), d = t*16 + hi*8 + j
    short8 qB[4];
    {
        const long qbase = (long)(b * 2048 + q0 + wv * 32 + l32) * 1024 + h * 64 + hi * 8;
#pragma unroll
        for (int t = 0; t < 4; t++) qB[t] = *(const short8*)&Q[qbase + t * 16];
    }

    const int sr = gtid >> 3;                         // 0..31
    const int scol = (((gtid & 7) ^ (sr & 7)) << 3);
    const short* Kp = Kb + (long)(b * 2048 + group * 1024) * 1024 + h * 64;
    const short* Vp = Vt + ((long)b << 21) + (long)h * 64 * 2048 + group * 1024;

    f32x16 o[2] = {};
    float lsum = 0.0f;

    // prologue: stage K tile 0 of this group's half
#pragma unroll
    for (int i = 0; i < 2; i++) {
        int r = i * 32 + sr;
        gload16(&Kp[(long)r * 1024 + scol], &Ks[group][0][i * 2048 + wv * 512]);
    }
    __syncthreads();

    for (int kt = 0; kt < 16; kt++) {
        const int cur = kt & 1;
        const int kb = kt * 64;

        // stage V(kt) — group's waves done reading Vs at previous end barrier
#pragma unroll
        for (int i = 0; i < 2; i++) {
            int r = i * 32 + sr;
            gload16(&Vp[(long)r * 2048 + kb + scol], &Vs[group][i * 2048 + wv * 512]);
        }

        // S^T: two 32(kv) x 32(q) tiles; exp2 + in-register bf16 pack.
        // lane holds P[kv = kvt*32 + 8*c + 4*hi + r'][q = l32];
        // c0[c] = bf16 pair (r'=0,1), c1[c] = bf16 pair (r'=2,3), c = kvt*4+g.
        u32 c0[8], c1[8];
#pragma unroll
        for (int kvt = 0; kvt < 2; kvt++) {
            const int row = kvt * 32 + l32;
            f32x16 st = {};
            __builtin_amdgcn_s_setprio(1);
#pragma unroll
            for (int step = 0; step < 4; step++) {
                short8 ak = *(short8*)&Ks[group][cur][row * 64 + (((step * 2 + hi) ^ sw) << 3)];
                st = __builtin_amdgcn_mfma_f32_32x32x16_bf16(ak, qB[step], st, 0, 0, 0);
            }
            __builtin_amdgcn_s_setprio(0);
#pragma unroll
            for (int g = 0; g < 4; g++) {
                float p0 = __builtin_amdgcn_exp2f(st[g * 4 + 0]);
                float p1 = __builtin_amdgcn_exp2f(st[g * 4 + 1]);
                float p2 = __builtin_amdgcn_exp2f(st[g * 4 + 2]);
                float p3 = __builtin_amdgcn_exp2f(st[g * 4 + 3]);
                lsum += (p0 + p1) + (p2 + p3);
                u32 w0, w1;
                asm("v_cvt_pk_bf16_f32 %0, %1, %2" : "=v"(w0) : "v"(p0), "v"(p1));
                asm("v_cvt_pk_bf16_f32 %0, %1, %2" : "=v"(w1) : "v"(p2), "v"(p3));
                c0[kvt * 4 + g] = w0;
                c1[kvt * 4 + g] = w1;
            }
        }

        // mid barrier: V(kt) drained & visible; all K[cur] reads done
        __syncthreads();

        // prefetch K(kt+1) — drained at end barrier
        if (kt < 15) {
            const int kbn = kb + 64;
#pragma unroll
            for (int i = 0; i < 2; i++) {
                int r = i * 32 + sr;
                gload16(&Kp[(long)(kbn + r) * 1024 + scol],
                        &Ks[group][cur ^ 1][i * 2048 + wv * 512]);
            }
        }

        // Build P B-frags in-register: step s needs kv = s*16 + hi*8 + j.
        // permlane32_swap(vdst,vsrc): vdst.row1 <-> vsrc.row0, so
        // r[0] = {own c(2s) | partner c(2s+1)}, r[1] = {partner c(2s) | own c(2s+1)}.
        short8 pB[4];
#pragma unroll
        for (int s = 0; s < 4; s++) {
            u32x2 r0 = __builtin_amdgcn_permlane32_swap(c0[2 * s], c0[2 * s + 1], false, false);
            u32x2 r1 = __builtin_amdgcn_permlane32_swap(c1[2 * s], c1[2 * s + 1], false, false);
            u32x4 bw;
            bw[0] = r0[0]; bw[1] = r1[0]; bw[2] = r0[1]; bw[3] = r1[1];
            pB[s] = __builtin_bit_cast(short8, bw);
        }

        // O^T = V^T . P^T : two 32(d) x 32(q) tiles
        __builtin_amdgcn_s_setprio(1);
#pragma unroll
        for (int dt = 0; dt < 2; dt++) {
            const int row = dt * 32 + l32;
#pragma unroll
            for (int s = 0; s < 4; s++) {
                short8 av = *(short8*)&Vs[group][row * 64 + (((s * 2 + hi) ^ sw) << 3)];
                o[dt] = __builtin_amdgcn_mfma_f32_32x32x16_bf16(av, pB[s], o[dt], 0, 0, 0);
            }
        }
        __builtin_amdgcn_s_setprio(0);

        // end barrier: K(kt+1) drained; Vs reads done
        __syncthreads();
    }

    // merge the two kv halves through LDS (reuse Ks as f32 buffer, Vs for lsum)
    lsum += __shfl_xor(lsum, 32, 64);
    float* cb = (float*)&Ks[0][0][0];    // 128 q x 64 d f32 = 32 KB
    float* lb = (float*)&Vs[0][0];       // 128 f32
    const int ql = wv * 32 + l32;
    if (group == 1) {
#pragma unroll
        for (int dt = 0; dt < 2; dt++) {
#pragma unroll
            for (int g = 0; g < 4; g++) {
                f32x4 v4;
#pragma unroll
                for (int i = 0; i < 4; i++) v4[i] = o[dt][g * 4 + i];
                *(f32x4*)&cb[ql * 64 + dt * 32 + g * 8 + hi * 4] = v4;
            }
        }
        if (hi == 0) lb[ql] = lsum;
    }
    __syncthreads();
    if (group == 0) {
        const float inv = 1.0f / (lsum + lb[ql]);
        const long rbase = (long)(b * 2048 + q0 + ql) * 1024 + h * 64;
#pragma unroll
        for (int dt = 0; dt < 2; dt++) {
#pragma unroll
            for (int g = 0; g < 4; g++) {
                const f32x4 pv = *(const f32x4*)&cb[ql * 64 + dt * 32 + g * 8 + hi * 4];
                short4v pk;
#pragma unroll
                for (int i = 0; i < 4; i++) pk[i] = f2bf((o[dt][g * 4 + i] + pv[i]) * inv);
                *(short4v*)&O[rbase + dt * 32 + g * 8 + hi * 4] = pk;
            }
        }
    }
}

// ---------------------------------------------------------------------------
// Final GEMM: out = AO @ Wc^T + bc, fp32 out. 64x128 tiles, BK=128 (two
// sub-tiles per barrier pair), swizzled. 512 blocks.
// ---------------------------------------------------------------------------
__global__ __launch_bounds__(256) void gemm_final(const short* __restrict__ A,
                                                  const short* __restrict__ W,
                                                  const float* __restrict__ bias,
                                                  float* __restrict__ C) {
    __shared__ short As[2][64 * 64];
    __shared__ short Bs[2][128 * 64];
    const int K = 1024;
    const int tid  = threadIdx.x;
    const int lane = tid & 63;
    const int wave = tid >> 6;
    const int quad = lane >> 4;
    const int l16  = lane & 15;
    const int bid = blockIdx.x;
    const int m0 = (bid >> 3) * 64;
    const int n0 = (bid & 7) * 128;
    const int wm = (wave >> 1) * 32;
    const int wn = (wave & 1) * 64;

    f32x4 acc[2][4] = {};
    const int sr = tid >> 3;
    const int scol = (((tid & 7) ^ (sr & 7)) << 3);
    const int fo_a = ((quad ^ (l16 & 7)) << 3);
    const int fo_b = (((4 + quad) ^ (l16 & 7)) << 3);

    for (int k0 = 0; k0 < K; k0 += 128) {
#pragma unroll
        for (int half = 0; half < 2; half++) {
            const int kk = k0 + half * 64;
#pragma unroll
            for (int i = 0; i < 2; i++) {
                int r = i * 32 + sr;
                gload16(&A[(long)(m0 + r) * K + kk + scol], &As[half][i * 2048 + wave * 512]);
            }
#pragma unroll
            for (int i = 0; i < 4; i++) {
                int r = i * 32 + sr;
                gload16(&W[(long)(n0 + r) * K + kk + scol], &Bs[half][i * 2048 + wave * 512]);
            }
        }
        __syncthreads();
#pragma unroll
        for (int half = 0; half < 2; half++) {
            short8 bfr[4][2];
#pragma unroll
            for (int ni = 0; ni < 4; ni++) {
                const int row = wn + ni * 16 + l16;
                bfr[ni][0] = *(short8*)&Bs[half][row * 64 + fo_a];
                bfr[ni][1] = *(short8*)&Bs[half][row * 64 + fo_b];
            }
#pragma unroll
            for (int mi = 0; mi < 2; mi++) {
                const int row = wm + mi * 16 + l16;
                short8 af0 = *(short8*)&As[half][row * 64 + fo_a];
                short8 af1 = *(short8*)&As[half][row * 64 + fo_b];
#pragma unroll
                for (int ni = 0; ni < 4; ni++) {
                    acc[mi][ni] = __builtin_amdgcn_mfma_f32_16x16x32_bf16(af0, bfr[ni][0],
                                                                          acc[mi][ni], 0, 0, 0);
                    acc[mi][ni] = __builtin_amdgcn_mfma_f32_16x16x32_bf16(af1, bfr[ni][1],
                                                                          acc[mi][ni], 0, 0, 0);
                }
            }
        }
        __syncthreads();
    }

#pragma unroll
    for (int mi = 0; mi < 2; mi++) {
#pragma unroll
        for (int ni = 0; ni < 4; ni++) {
            const int n = n0 + wn + ni * 16 + l16;
            const float bv = bias[n];
            const int mbase = m0 + wm + mi * 16 + quad * 4;
#pragma unroll
            for (int r = 0; r < 4; r++)
                C[(long)(mbase + r) * 1024 + n] = acc[mi][ni][r] + bv;
        }
    }
}

// ---------------------------------------------------------------------------
extern "C" void kernel_launch(void* const* d_in, const int* in_sizes, int n_in,
                              void* d_out, int out_size, void* d_ws, size_t ws_size,
                              hipStream_t stream) {
    const float* X  = (const float*)d_in[0];
    const float* Wq = (const float*)d_in[1];
    const float* bq = (const float*)d_in[2];
    const float* Wk = (const float*)d_in[3];
    const float* bk = (const float*)d_in[4];
    const float* Wv = (const float*)d_in[5];
    const float* bv = (const float*)d_in[6];
    const float* Ws = (const float*)d_in[7];
    const float* bs = (const float*)d_in[8];
    const float* Wo = (const float*)d_in[9];
    const float* bo = (const float*)d_in[10];

    char* ws = (char*)d_ws;
    const long MB = 1 << 20;
    short* Xb   = (short*)(ws + 0 * MB);   // 8 MB; reused as AO after QKV
    short* Wcat = (short*)(ws + 8 * MB);   // 6 MB (Wq,Wk,Wv bf16)
    short* WmT  = (short*)(ws + 14 * MB);  // 2 MB
    short* Wob  = (short*)(ws + 16 * MB);  // 2 MB
    short* Wc   = (short*)(ws + 18 * MB);  // 2 MB
    float* bc   = (float*)(ws + 20 * MB);  // 4 KB
    short* Qb   = (short*)(ws + 21 * MB);  // 8 MB
    short* Kbf  = (short*)(ws + 29 * MB);  // 8 MB
    short* Vtb  = (short*)(ws + 37 * MB);  // 8 MB
    short* AO   = Xb;

    dim3 bb(256);

    prep<<<dim3(2560), bb, 0, stream>>>(X, Wq, Wk, Wv, Wo, Ws, bs, bo,
                                        Xb, Wcat, Wob, WmT, bc);
    gemm_qkvwc<<<dim3(1664), bb, 0, stream>>>(Xb, Wcat, Wob, WmT, bq, bk, bv,
                                              Qb, Kbf, Vtb, Wc);
    attn_kernel<<<dim3(16, 16, 2), dim3(512), 0, stream>>>(Qb, Kbf, Vtb, AO);
    gemm_final<<<dim3(512), bb, 0, stream>>>(AO, Wc, bc, (float*)d_out);
}

// Round 5
// 199.019 us; speedup vs baseline: 1.1638x; 1.0540x over previous
//
#include <hip/hip_runtime.h>
#include <stdint.h>

typedef __attribute__((ext_vector_type(8))) short short8;
typedef __attribute__((ext_vector_type(4))) short short4v;
typedef __attribute__((ext_vector_type(4))) float f32x4;
typedef __attribute__((ext_vector_type(16))) float f32x16;
typedef __attribute__((ext_vector_type(2))) unsigned int u32x2;
typedef __attribute__((ext_vector_type(4))) unsigned int u32x4;
typedef unsigned int u32;
typedef const __attribute__((address_space(1))) u32* gas_ptr;
typedef __attribute__((address_space(3))) u32* las_ptr;

#define QSCALE 0.18033688011112042f   // 0.125 * log2(e)

__device__ inline short f2bf(float x) {
    u32 u = __float_as_uint(x);
    u = u + 0x7FFFu + ((u >> 16) & 1u);   // RNE
    return (short)(u >> 16);
}
__device__ inline void gload16(const void* g, const void* l) {
    __builtin_amdgcn_global_load_lds((gas_ptr)g, (las_ptr)l, 16, 0, 0);
}

// ---------------------------------------------------------------------------
// prep: all fp32->bf16 converts + strata fold (transposed) + bc matvec.
// ---------------------------------------------------------------------------
__global__ __launch_bounds__(256) void prep(const float* __restrict__ X,
                                            const float* __restrict__ Wq,
                                            const float* __restrict__ Wk,
                                            const float* __restrict__ Wv,
                                            const float* __restrict__ Wo,
                                            const float* __restrict__ Ws,
                                            const float* __restrict__ bs,
                                            const float* __restrict__ bo,
                                            short* __restrict__ Xb,
                                            short* __restrict__ Wcat,
                                            short* __restrict__ Wob,
                                            short* __restrict__ WmT,
                                            float* __restrict__ bc) {
    __shared__ short T[64][65];
    const int tid = threadIdx.x;
    const int bid = blockIdx.x;
    if (bid < 2048) {
#pragma unroll
        for (int c = 0; c < 4; c++) {
            const int chunk = bid * 4 + c;
            const float* src;
            short* dst;
            int rel;
            if (chunk < 4096)      { src = X;  dst = Xb;                rel = chunk; }
            else if (chunk < 5120) { src = Wq; dst = Wcat;              rel = chunk - 4096; }
            else if (chunk < 6144) { src = Wk; dst = Wcat + (1 << 20);  rel = chunk - 5120; }
            else if (chunk < 7168) { src = Wv; dst = Wcat + (2 << 20);  rel = chunk - 6144; }
            else                   { src = Wo; dst = Wob;               rel = chunk - 7168; }
            int i = (rel * 256 + tid) * 4;
            float4 v = *(const float4*)&src[i];
            short4v o;
            o[0] = f2bf(v.x); o[1] = f2bf(v.y); o[2] = f2bf(v.z); o[3] = f2bf(v.w);
            *(short4v*)&dst[i] = o;
        }
    } else if (bid < 2304) {
        const int id = bid - 2048;
        const int gx = (id & 15) * 64, jy = (id >> 4) * 64;
        const int HH = 1 << 20;
        for (int e = tid; e < 4096; e += 256) {
            int j = e >> 6, g = e & 63;
            int idx = (jy + j) * 1024 + gx + g;
            float v = (Ws[idx] + Ws[idx + HH] + Ws[idx + 2 * HH]) * (1.0f / 3.0f);
            T[g][j] = f2bf(v);
        }
        __syncthreads();
        for (int e = tid; e < 4096; e += 256) {
            int g = e >> 6, j = e & 63;
            WmT[(long)(gx + g) * 1024 + jy + j] = T[g][j];
        }
    } else {
        const int lane = tid & 63;
        const int n = (bid - 2304) * 4 + (tid >> 6);
        float acc = 0.0f;
        for (int j0 = 0; j0 < 1024; j0 += 64) {
            int j = j0 + lane;
            float bm = (bs[j] + bs[j + 1024] + bs[j + 2048]) * (1.0f / 3.0f);
            acc += Wo[(long)n * 1024 + j] * bm;
        }
#pragma unroll
        for (int off = 1; off < 64; off <<= 1) acc += __shfl_xor(acc, off, 64);
        if (lane == 0) bc[n] = acc + bo[n];
    }
}

// ---------------------------------------------------------------------------
// Fused QKV + Wc GEMM, 64x128 tiles, BK=64, XOR-8 swizzled LDS. 1664 blocks.
// XCD-chunked block swizzle: 208 consecutive logical blocks per XCD so X
// m-panels and W n-panels stay resident in that XCD's private L2.
// Q pre-scaled by QSCALE; V stored transposed per-head.
// ---------------------------------------------------------------------------
__global__ __launch_bounds__(256) void gemm_qkvwc(const short* __restrict__ Xb,
                                                  const short* __restrict__ Wcat,
                                                  const short* __restrict__ Wob,
                                                  const short* __restrict__ WmT,
                                                  const float* __restrict__ bq,
                                                  const float* __restrict__ bk,
                                                  const float* __restrict__ bv,
                                                  short* __restrict__ Qb,
                                                  short* __restrict__ Kb,
                                                  short* __restrict__ Vt,
                                                  short* __restrict__ Wc) {
    __shared__ short As[64 * 64];
    __shared__ short Bs[128 * 64];
    const int K = 1024;
    const int tid  = threadIdx.x;
    const int lane = tid & 63;
    const int wave = tid >> 6;
    const int quad = lane >> 4;
    const int l16  = lane & 15;
    // T1: HW round-robins blockIdx%8 across XCDs -> give each XCD a
    // contiguous 208-block chunk of the logical (sel,m,n) space.
    const int bid = (blockIdx.x & 7) * 208 + (blockIdx.x >> 3);
    const short *A, *W;
    int m0, n0, sel;
    if (bid < 1536) {
        sel = bid >> 9;
        int r = bid & 511;
        m0 = (r >> 3) * 64;
        n0 = (r & 7) * 128;
        A = Xb;
        W = Wcat + (long)sel * (1 << 20);
    } else {
        int w = bid - 1536;
        sel = 3;
        m0 = (w >> 3) * 64;
        n0 = (w & 7) * 128;
        A = Wob;
        W = WmT;
    }
    const int wm = (wave >> 1) * 32;
    const int wn = (wave & 1) * 64;

    f32x4 acc[2][4] = {};
    const int sr = tid >> 3;
    const int scol = (((tid & 7) ^ (sr & 7)) << 3);
    const int fo_a = ((quad ^ (l16 & 7)) << 3);
    const int fo_b = (((4 + quad) ^ (l16 & 7)) << 3);

    for (int k0 = 0; k0 < K; k0 += 64) {
#pragma unroll
        for (int i = 0; i < 2; i++) {
            int r = i * 32 + sr;
            gload16(&A[(long)(m0 + r) * K + k0 + scol], &As[i * 2048 + wave * 512]);
        }
#pragma unroll
        for (int i = 0; i < 4; i++) {
            int r = i * 32 + sr;
            gload16(&W[(long)(n0 + r) * K + k0 + scol], &Bs[i * 2048 + wave * 512]);
        }
        __syncthreads();
        short8 bfr[4][2];
#pragma unroll
        for (int ni = 0; ni < 4; ni++) {
            const int row = wn + ni * 16 + l16;
            bfr[ni][0] = *(short8*)&Bs[row * 64 + fo_a];
            bfr[ni][1] = *(short8*)&Bs[row * 64 + fo_b];
        }
#pragma unroll
        for (int mi = 0; mi < 2; mi++) {
            const int row = wm + mi * 16 + l16;
            short8 af0 = *(short8*)&As[row * 64 + fo_a];
            short8 af1 = *(short8*)&As[row * 64 + fo_b];
#pragma unroll
            for (int ni = 0; ni < 4; ni++) {
                acc[mi][ni] = __builtin_amdgcn_mfma_f32_16x16x32_bf16(af0, bfr[ni][0],
                                                                      acc[mi][ni], 0, 0, 0);
                acc[mi][ni] = __builtin_amdgcn_mfma_f32_16x16x32_bf16(af1, bfr[ni][1],
                                                                      acc[mi][ni], 0, 0, 0);
            }
        }
        __syncthreads();
    }

#pragma unroll
    for (int mi = 0; mi < 2; mi++) {
#pragma unroll
        for (int ni = 0; ni < 4; ni++) {
            const int n = n0 + wn + ni * 16 + l16;
            const int mbase = m0 + wm + mi * 16 + quad * 4;
            float bv2 = 0.0f;
            if (sel == 0) bv2 = bq[n];
            else if (sel == 1) bv2 = bk[n];
            else if (sel == 2) bv2 = bv[n];
            if (sel == 2) {
                short4v pk;
#pragma unroll
                for (int r = 0; r < 4; r++) pk[r] = f2bf(acc[mi][ni][r] + bv2);
                long addr = ((long)(mbase >> 11) << 21) + (long)n * 2048 + (mbase & 2047);
                *(short4v*)&Vt[addr] = pk;
            } else if (sel == 0) {
#pragma unroll
                for (int r = 0; r < 4; r++)
                    Qb[(long)(mbase + r) * 1024 + n] = f2bf((acc[mi][ni][r] + bv2) * QSCALE);
            } else {
                short* C = (sel == 1) ? Kb : Wc;
#pragma unroll
                for (int r = 0; r < 4; r++)
                    C[(long)(mbase + r) * 1024 + n] = f2bf(acc[mi][ni][r] + bv2);
            }
        }
    }
}

// ---------------------------------------------------------------------------
// Flash attention v4 + T5 setprio: 32x32x16 MFMA, block = 128 q x 8 waves.
// Intra-block KV split: waves 0-3 -> kv [0,1024), waves 4-7 -> kv [1024,2048),
// each group double-buffers its own K and single-buffers its own V (48 KB LDS).
// P kept fully in registers via v_cvt_pk_bf16_f32 + permlane32_swap.
// XCD-chunked swizzle: one XCD serves 64 consecutive logical blocks =
// {16 q-tiles} x {4 heads} of one batch -> K/V working set 2 MB, L2-resident.
// grid 512 (flat).
// ---------------------------------------------------------------------------
__global__ __launch_bounds__(512, 4) void attn_kernel(const short* __restrict__ Q,
                                                      const short* __restrict__ Kb,
                                                      const short* __restrict__ Vt,
                                                      short* __restrict__ O) {
    __shared__ short Ks[2][2][64 * 64];   // [group][buf] 32 KB
    __shared__ short Vs[2][64 * 64];      // [group]      16 KB
    const int tid   = threadIdx.x;
    const int lane  = tid & 63;
    const int wave  = tid >> 6;       // 0..7
    const int group = wave >> 2;      // kv half
    const int wv    = wave & 3;       // q sub-tile within block
    const int gtid  = tid & 255;      // id within group
    const int l32   = lane & 31;
    const int hi    = lane >> 5;
    const int sw    = l32 & 7;
    // T1 chunked swizzle over flat 512-block grid
    const int swz = (blockIdx.x & 7) * 64 + (blockIdx.x >> 3);
    const int q0 = (swz & 15) * 128;
    const int h  = (swz >> 4) & 15;
    const int b  = swz >> 8;

    // Q B-frags: B[k=d][n=q], lane: q=l32 (own row), d = t*16 + hi*8 + j
    short8 qB[4];
    {
        const long qbase = (long)(b * 2048 + q0 + wv * 32 + l32) * 1024 + h * 64 + hi * 8;
#pragma unroll
        for (int t = 0; t < 4; t++) qB[t] = *(const short8*)&Q[qbase + t * 16];
    }

    const int sr = gtid >> 3;                         // 0..31
    const int scol = (((gtid & 7) ^ (sr & 7)) << 3);
    const short* Kp = Kb + (long)(b * 2048 + group * 1024) * 1024 + h * 64;
    const short* Vp = Vt + ((long)b << 21) + (long)h * 64 * 2048 + group * 1024;

    f32x16 o[2] = {};
    float lsum = 0.0f;

    // prologue: stage K tile 0 of this group's half
#pragma unroll
    for (int i = 0; i < 2; i++) {
        int r = i * 32 + sr;
        gload16(&Kp[(long)r * 1024 + scol], &Ks[group][0][i * 2048 + wv * 512]);
    }
    __syncthreads();

    for (int kt = 0; kt < 16; kt++) {
        const int cur = kt & 1;
        const int kb = kt * 64;

        // stage V(kt) — group's waves done reading Vs at previous end barrier
#pragma unroll
        for (int i = 0; i < 2; i++) {
            int r = i * 32 + sr;
            gload16(&Vp[(long)r * 2048 + kb + scol], &Vs[group][i * 2048 + wv * 512]);
        }

        // S^T: two 32(kv) x 32(q) tiles; exp2 + in-register bf16 pack.
        // lane holds P[kv = kvt*32 + 8*c + 4*hi + r'][q = l32];
        // c0[c] = bf16 pair (r'=0,1), c1[c] = bf16 pair (r'=2,3), c = kvt*4+g.
        u32 c0[8], c1[8];
#pragma unroll
        for (int kvt = 0; kvt < 2; kvt++) {
            const int row = kvt * 32 + l32;
            f32x16 st = {};
            __builtin_amdgcn_s_setprio(1);
#pragma unroll
            for (int step = 0; step < 4; step++) {
                short8 ak = *(short8*)&Ks[group][cur][row * 64 + (((step * 2 + hi) ^ sw) << 3)];
                st = __builtin_amdgcn_mfma_f32_32x32x16_bf16(ak, qB[step], st, 0, 0, 0);
            }
            __builtin_amdgcn_s_setprio(0);
#pragma unroll
            for (int g = 0; g < 4; g++) {
                float p0 = __builtin_amdgcn_exp2f(st[g * 4 + 0]);
                float p1 = __builtin_amdgcn_exp2f(st[g * 4 + 1]);
                float p2 = __builtin_amdgcn_exp2f(st[g * 4 + 2]);
                float p3 = __builtin_amdgcn_exp2f(st[g * 4 + 3]);
                lsum += (p0 + p1) + (p2 + p3);
                u32 w0, w1;
                asm("v_cvt_pk_bf16_f32 %0, %1, %2" : "=v"(w0) : "v"(p0), "v"(p1));
                asm("v_cvt_pk_bf16_f32 %0, %1, %2" : "=v"(w1) : "v"(p2), "v"(p3));
                c0[kvt * 4 + g] = w0;
                c1[kvt * 4 + g] = w1;
            }
        }

        // mid barrier: V(kt) drained & visible; all K[cur] reads done
        __syncthreads();

        // prefetch K(kt+1) — drained at end barrier
        if (kt < 15) {
            const int kbn = kb + 64;
#pragma unroll
            for (int i = 0; i < 2; i++) {
                int r = i * 32 + sr;
                gload16(&Kp[(long)(kbn + r) * 1024 + scol],
                        &Ks[group][cur ^ 1][i * 2048 + wv * 512]);
            }
        }

        // Build P B-frags in-register: step s needs kv = s*16 + hi*8 + j.
        // permlane32_swap(vdst,vsrc): vdst.row1 <-> vsrc.row0, so
        // r[0] = {own c(2s) | partner c(2s+1)}, r[1] = {partner c(2s) | own c(2s+1)}.
        short8 pB[4];
#pragma unroll
        for (int s = 0; s < 4; s++) {
            u32x2 r0 = __builtin_amdgcn_permlane32_swap(c0[2 * s], c0[2 * s + 1], false, false);
            u32x2 r1 = __builtin_amdgcn_permlane32_swap(c1[2 * s], c1[2 * s + 1], false, false);
            u32x4 bw;
            bw[0] = r0[0]; bw[1] = r1[0]; bw[2] = r0[1]; bw[3] = r1[1];
            pB[s] = __builtin_bit_cast(short8, bw);
        }

        // O^T = V^T . P^T : two 32(d) x 32(q) tiles
        __builtin_amdgcn_s_setprio(1);
#pragma unroll
        for (int dt = 0; dt < 2; dt++) {
            const int row = dt * 32 + l32;
#pragma unroll
            for (int s = 0; s < 4; s++) {
                short8 av = *(short8*)&Vs[group][row * 64 + (((s * 2 + hi) ^ sw) << 3)];
                o[dt] = __builtin_amdgcn_mfma_f32_32x32x16_bf16(av, pB[s], o[dt], 0, 0, 0);
            }
        }
        __builtin_amdgcn_s_setprio(0);

        // end barrier: K(kt+1) drained; Vs reads done
        __syncthreads();
    }

    // merge the two kv halves through LDS (reuse Ks as f32 buffer, Vs for lsum)
    lsum += __shfl_xor(lsum, 32, 64);
    float* cb = (float*)&Ks[0][0][0];    // 128 q x 64 d f32 = 32 KB
    float* lb = (float*)&Vs[0][0];       // 128 f32
    const int ql = wv * 32 + l32;
    if (group == 1) {
#pragma unroll
        for (int dt = 0; dt < 2; dt++) {
#pragma unroll
            for (int g = 0; g < 4; g++) {
                f32x4 v4;
#pragma unroll
                for (int i = 0; i < 4; i++) v4[i] = o[dt][g * 4 + i];
                *(f32x4*)&cb[ql * 64 + dt * 32 + g * 8 + hi * 4] = v4;
            }
        }
        if (hi == 0) lb[ql] = lsum;
    }
    __syncthreads();
    if (group == 0) {
        const float inv = 1.0f / (lsum + lb[ql]);
        const long rbase = (long)(b * 2048 + q0 + ql) * 1024 + h * 64;
#pragma unroll
        for (int dt = 0; dt < 2; dt++) {
#pragma unroll
            for (int g = 0; g < 4; g++) {
                const f32x4 pv = *(const f32x4*)&cb[ql * 64 + dt * 32 + g * 8 + hi * 4];
                short4v pk;
#pragma unroll
                for (int i = 0; i < 4; i++) pk[i] = f2bf((o[dt][g * 4 + i] + pv[i]) * inv);
                *(short4v*)&O[rbase + dt * 32 + g * 8 + hi * 4] = pk;
            }
        }
    }
}

// ---------------------------------------------------------------------------
// Final GEMM: out = AO @ Wc^T + bc, fp32 out. 64x128 tiles, BK=64, swizzled.
// 512 blocks, XCD-chunked (64/XCD: Wc fully L2-resident per XCD).
// ---------------------------------------------------------------------------
__global__ __launch_bounds__(256) void gemm_final(const short* __restrict__ A,
                                                  const short* __restrict__ W,
                                                  const float* __restrict__ bias,
                                                  float* __restrict__ C) {
    __shared__ short As[64 * 64];
    __shared__ short Bs[128 * 64];
    const int K = 1024;
    const int tid  = threadIdx.x;
    const int lane = tid & 63;
    const int wave = tid >> 6;
    const int quad = lane >> 4;
    const int l16  = lane & 15;
    const int bid = (blockIdx.x & 7) * 64 + (blockIdx.x >> 3);   // T1 chunked
    const int m0 = (bid >> 3) * 64;
    const int n0 = (bid & 7) * 128;
    const int wm = (wave >> 1) * 32;
    const int wn = (wave & 1) * 64;

    f32x4 acc[2][4] = {};
    const int sr = tid >> 3;
    const int scol = (((tid & 7) ^ (sr & 7)) << 3);
    const int fo_a = ((quad ^ (l16 & 7)) << 3);
    const int fo_b = (((4 + quad) ^ (l16 & 7)) << 3);

    for (int k0 = 0; k0 < K; k0 += 64) {
#pragma unroll
        for (int i = 0; i < 2; i++) {
            int r = i * 32 + sr;
            gload16(&A[(long)(m0 + r) * K + k0 + scol], &As[i * 2048 + wave * 512]);
        }
#pragma unroll
        for (int i = 0; i < 4; i++) {
            int r = i * 32 + sr;
            gload16(&W[(long)(n0 + r) * K + k0 + scol], &Bs[i * 2048 + wave * 512]);
        }
        __syncthreads();
        short8 bfr[4][2];
#pragma unroll
        for (int ni = 0; ni < 4; ni++) {
            const int row = wn + ni * 16 + l16;
            bfr[ni][0] = *(short8*)&Bs[row * 64 + fo_a];
            bfr[ni][1] = *(short8*)&Bs[row * 64 + fo_b];
        }
#pragma unroll
        for (int mi = 0; mi < 2; mi++) {
            const int row = wm + mi * 16 + l16;
            short8 af0 = *(short8*)&As[row * 64 + fo_a];
            short8 af1 = *(short8*)&As[row * 64 + fo_b];
#pragma unroll
            for (int ni = 0; ni < 4; ni++) {
                acc[mi][ni] = __builtin_amdgcn_mfma_f32_16x16x32_bf16(af0, bfr[ni][0],
                                                                      acc[mi][ni], 0, 0, 0);
                acc[mi][ni] = __builtin_amdgcn_mfma_f32_16x16x32_bf16(af1, bfr[ni][1],
                                                                      acc[mi][ni], 0, 0, 0);
            }
        }
        __syncthreads();
    }

#pragma unroll
    for (int mi = 0; mi < 2; mi++) {
#pragma unroll
        for (int ni = 0; ni < 4; ni++) {
            const int n = n0 + wn + ni * 16 + l16;
            const float bv = bias[n];
            const int mbase = m0 + wm + mi * 16 + quad * 4;
#pragma unroll
            for (int r = 0; r < 4; r++)
                C[(long)(mbase + r) * 1024 + n] = acc[mi][ni][r] + bv;
        }
    }
}

// ---------------------------------------------------------------------------
extern "C" void kernel_launch(void* const* d_in, const int* in_sizes, int n_in,
                              void* d_out, int out_size, void* d_ws, size_t ws_size,
                              hipStream_t stream) {
    const float* X  = (const float*)d_in[0];
    const float* Wq = (const float*)d_in[1];
    const float* bq = (const float*)d_in[2];
    const float* Wk = (const float*)d_in[3];
    const float* bk = (const float*)d_in[4];
    const float* Wv = (const float*)d_in[5];
    const float* bv = (const float*)d_in[6];
    const float* Ws = (const float*)d_in[7];
    const float* bs = (const float*)d_in[8];
    const float* Wo = (const float*)d_in[9];
    const float* bo = (const float*)d_in[10];

    char* ws = (char*)d_ws;
    const long MB = 1 << 20;
    short* Xb   = (short*)(ws + 0 * MB);   // 8 MB; reused as AO after QKV
    short* Wcat = (short*)(ws + 8 * MB);   // 6 MB (Wq,Wk,Wv bf16)
    short* WmT  = (short*)(ws + 14 * MB);  // 2 MB
    short* Wob  = (short*)(ws + 16 * MB);  // 2 MB
    short* Wc   = (short*)(ws + 18 * MB);  // 2 MB
    float* bc   = (float*)(ws + 20 * MB);  // 4 KB
    short* Qb   = (short*)(ws + 21 * MB);  // 8 MB
    short* Kbf  = (short*)(ws + 29 * MB);  // 8 MB
    short* Vtb  = (short*)(ws + 37 * MB);  // 8 MB
    short* AO   = Xb;

    dim3 bb(256);

    prep<<<dim3(2560), bb, 0, stream>>>(X, Wq, Wk, Wv, Wo, Ws, bs, bo,
                                        Xb, Wcat, Wob, WmT, bc);
    gemm_qkvwc<<<dim3(1664), bb, 0, stream>>>(Xb, Wcat, Wob, WmT, bq, bk, bv,
                                              Qb, Kbf, Vtb, Wc);
    attn_kernel<<<dim3(512), dim3(512), 0, stream>>>(Qb, Kbf, Vtb, AO);
    gemm_final<<<dim3(512), bb, 0, stream>>>(AO, Wc, bc, (float*)d_out);
}